// Round 16
// baseline (42.466 us; speedup 1.0000x reference)
//
#include <hip/hip_runtime.h>
#include <math.h>

#define NNODE 512
#define NBATCH 4
#define NFEAT 12
#define QKD 128
#define NVD 128
#define EVD 32
#define CATD 160          // NVD + EVD
#define CATB 168          // catb LDS stride (bf16)
#define TRD 256
#define NCLS 5
#define NROWS 2048        // NBATCH * NNODE
#define EPSV 1e-5f
#define NSTATBUF 8        // split BN-stat atomic contention 8 ways
#define NCHUNK 4          // j-chunks (online-softmax loop)
#define JC 128            // j-chunk width
#define RPB 4             // query rows per attnTrans block (512 blocks)
#define QR 8              // rows per qkv block
#define SSW 132           // sS row stride (f32)
#define WBW 136           // sWb row stride (ushort)

typedef float floatx4 __attribute__((ext_vector_type(4)));
typedef __bf16 bf16x8 __attribute__((ext_vector_type(8)));
typedef unsigned short ushort_t;
typedef ushort_t ushort4v __attribute__((ext_vector_type(4)));

// f32 -> bf16 bits, round-to-nearest-even
static __device__ __forceinline__ ushort_t f2bf(float x) {
  unsigned int u = __float_as_uint(x);
  return (ushort_t)((u + 0x7fffu + ((u >> 16) & 1u)) >> 16);
}
// fragment k-order slot within a 32-block: lane kg holds logical k
// {4kg..4kg+3, 16+4kg..16+4kg+3}; slot32 places those 8 contiguously.
static __device__ __forceinline__ int slot32(int r) {   // r in 0..31
  return ((r & 15) >> 2) * 8 + (r & 3) + ((r >> 4) << 2);
}
static __device__ __forceinline__ int kslot(int k) {    // block-preserving
  return (k & ~31) + slot32(k & 31);
}

// ---------------------------------------------------------------------------
// Kernel 1: projections -> bf16 Qb[row][slot(d)], Kb[row][slot(d)],
// NVT[b][d][jslot], Wtb[o][slot(k)]. 256 blocks x 256 thr, 8 rows/block.
// ---------------------------------------------------------------------------
__global__ __launch_bounds__(256) void qkv_kernel(
    const float* __restrict__ nodes,
    const float* __restrict__ Wq, const float* __restrict__ bq,
    const float* __restrict__ Wk, const float* __restrict__ bk,
    const float* __restrict__ Wnv, const float* __restrict__ bnv,
    const float* __restrict__ Wt,
    ushort_t* __restrict__ Qb, ushort_t* __restrict__ Kb,
    ushort_t* __restrict__ NVT, ushort_t* __restrict__ Wtb,
    float* __restrict__ stats) {
  const int tid = threadIdx.x;
  const int blk = blockIdx.x;           // 0..255
  const int rowbase = blk * QR;
  const int b = rowbase >> 9;
  const int jloc = rowbase & (NNODE - 1);
  if (blk < 2 * NSTATBUF) stats[blk * 256 + tid] = 0.f;   // 16x256 = 4096
  // Wt -> bf16 slot-permuted: one o-row (o = blk) per block.
  if (tid < CATD)
    Wtb[(size_t)blk * CATD + kslot(tid)] = f2bf(Wt[(size_t)blk * CATD + tid]);
  __shared__ float sn[QR][NFEAT];
  if (tid < QR * NFEAT) ((float*)sn)[tid] = nodes[(size_t)rowbase * NFEAT + tid];
  __syncthreads();

  // ---- Q/K: thread owns d = tid&127; rows (tid>>7)*4 .. +3 --------------
  {
    const int d  = tid & 127;
    const int rg = tid >> 7;
    const int sd = kslot(d);            // permuted column
    float wq[NFEAT], wk[NFEAT];
#pragma unroll
    for (int k = 0; k < NFEAT; ++k) {
      wq[k] = Wq[d * NFEAT + k];
      wk[k] = Wk[d * NFEAT + k];
    }
    const float bqv = bq[d], bkv = bk[d];
#pragma unroll
    for (int rr = 0; rr < 4; ++rr) {
      const int rl = rg * 4 + rr;
      float aq = bqv, ak = bkv;
#pragma unroll
      for (int k = 0; k < NFEAT; ++k) {
        const float n = sn[rl][k];
        aq = fmaf(n, wq[k], aq);
        ak = fmaf(n, wk[k], ak);
      }
      Qb[(size_t)(rowbase + rl) * QKD + sd] = f2bf(aq);
      Kb[(size_t)(rowbase + rl) * QKD + sd] = f2bf(ak);
    }
  }
  // ---- NV^T: thread owns d = tid>>1, half = tid&1 (4 j each, j-slotted) --
  {
    const int d    = tid >> 1;
    const int half = tid & 1;
    float wnv[NFEAT];
#pragma unroll
    for (int k = 0; k < NFEAT; ++k) wnv[k] = Wnv[d * NFEAT + k];
    const float bnvv = bnv[d];
    ushort4v v;
#pragma unroll
    for (int e = 0; e < 4; ++e) {
      const int rl = half * 4 + e;
      float av = bnvv;
#pragma unroll
      for (int k = 0; k < NFEAT; ++k) av = fmaf(sn[rl][k], wnv[k], av);
      v[e] = f2bf(av);
    }
    const int js = jloc + half * 4;     // 4-aligned; slot(js+e)=slot(js)+e
    const int jsl = (js & ~31) + slot32(js & 31);
    *(ushort4v*)(NVT + (size_t)b * QKD * NNODE + (size_t)d * NNODE + jsl) = v;
  }
}

// ---------------------------------------------------------------------------
// Kernel 2: attnTrans — flash attention, lean data path, 2 blocks/CU.
// 512 blocks x 256 thr (4 waves); block = 4 query rows x all 512 j.
// Wave wv owns j-tiles {2wv,2wv+1} (QK^T) and d-tiles {2wv,2wv+1} (PV),
// and softmax row wv. Real rows 0..3 (kg==0); garbage rows contained.
// ---------------------------------------------------------------------------
__global__ __launch_bounds__(256) void attnTrans_kernel(
    const ushort_t* __restrict__ Qb, const ushort_t* __restrict__ Kb,
    const ushort_t* __restrict__ NVT,
    const float* __restrict__ edges, const float* __restrict__ dist,
    const int* __restrict__ mask,
    const float* __restrict__ Wev, const float* __restrict__ bev,
    const ushort_t* __restrict__ Wtb, const float* __restrict__ bt,
    float* __restrict__ vals, float* __restrict__ stats) {
  __shared__ __align__(16) float sS[2][RPB][SSW];      // 4.2 KB (scores)
  __shared__ __align__(16) ushort_t sWb[2][16][WBW];   // 8.7 KB (bf16 w)
  __shared__ __align__(16) ushort_t catb[RPB * CATB];  // 1.3 KB
  __shared__ float sF[16], sF2[RPB], sSe[RPB], sSw[RPB];

  const int tid = threadIdx.x;
  const int bid = blockIdx.x;            // 0..511
  const int b   = bid >> 7;              // batch
  const int rg  = bid & 127;             // row group
  const int rowbase = b * NNODE + rg * RPB;

  const int lane = tid & 63;
  const int wv   = tid >> 6;             // wave 0..3
  const int col  = lane & 15;
  const int kg   = lane >> 4;

  if (tid < 16) sF[tid] = 0.f;           // rows 4..15 stay 0 forever

  const int jl0 = (wv * 2) * 16 + col;   // chunk-local j, tile 0
  const int jl1 = jl0 + 16;              // tile 1
  const int dp0 = (wv * 2) * 16 + col;   // d column, tile 0
  const int dp1 = dp0 + 16;              // tile 1

  // ---- Q A-fragments: single b128 each (slot-permuted Qb) ----------------
  bf16x8 aq[4];
  {
    const ushort_t* Qr = Qb + (size_t)(rowbase + (col & 3)) * QKD;
#pragma unroll
    for (int ks = 0; ks < 4; ++ks)
      aq[ks] = *(const bf16x8*)(Qr + ks * 32 + kg * 8);
  }

  // ---- 2-state prefetch registers ---------------------------------------
  bf16x8 kf[2][2][4], nf[2][2][4];
  float dd0[2][4], dd1[2][4];
  int   mm0[2][4], mm1[2][4];
  float ee0[2], ee1[2];
  {  // chunk 0
    const ushort_t* K0 = Kb + (size_t)(b * NNODE + jl0) * QKD;
    const ushort_t* K1 = Kb + (size_t)(b * NNODE + jl1) * QKD;
    const ushort_t* N0 = NVT + ((size_t)b * QKD + dp0) * NNODE;
    const ushort_t* N1 = NVT + ((size_t)b * QKD + dp1) * NNODE;
#pragma unroll
    for (int ks = 0; ks < 4; ++ks) {
      kf[0][0][ks] = *(const bf16x8*)(K0 + ks * 32 + kg * 8);
      kf[0][1][ks] = *(const bf16x8*)(K1 + ks * 32 + kg * 8);
      nf[0][0][ks] = *(const bf16x8*)(N0 + ks * 32 + kg * 8);
      nf[0][1][ks] = *(const bf16x8*)(N1 + ks * 32 + kg * 8);
    }
    if (kg == 0) {
#pragma unroll
      for (int r = 0; r < 4; ++r) {
        const size_t off = (size_t)(rowbase + r) * NNODE;
        dd0[0][r] = dist[off + jl0]; mm0[0][r] = mask[off + jl0];
        dd1[0][r] = dist[off + jl1]; mm1[0][r] = mask[off + jl1];
      }
    } else {
#pragma unroll
      for (int r = 0; r < 4; ++r) {
        dd0[0][r] = 0.f; mm0[0][r] = 0;
        dd1[0][r] = 0.f; mm1[0][r] = 0;
      }
    }
    ee0[0] = edges[(size_t)(rowbase + wv) * NNODE + lane];
    ee1[0] = edges[(size_t)(rowbase + wv) * NNODE + 64 + lane];
  }

  float m_run = -__builtin_inff(), l_run = 0.f, se_run = 0.f;  // row = wv
  floatx4 acc0 = {0.f, 0.f, 0.f, 0.f};   // PV acc d-tile 0 (rows kg*4+r)
  floatx4 acc1 = {0.f, 0.f, 0.f, 0.f};   // PV acc d-tile 1
  const float coeff = 0.0883883476483184f;  // 1/sqrt(128)

#pragma unroll
  for (int c = 0; c < NCHUNK; ++c) {
    const int cur = c & 1, nxt = (c + 1) & 1;
    // ---- issue chunk c+1 loads (in flight across this chunk) ------------
    if (c + 1 < NCHUNK) {
      const int jb2 = (c + 1) * JC;
      const ushort_t* K0 = Kb + (size_t)(b * NNODE + jb2 + jl0) * QKD;
      const ushort_t* K1 = Kb + (size_t)(b * NNODE + jb2 + jl1) * QKD;
      const ushort_t* N0 = NVT + ((size_t)b * QKD + dp0) * NNODE + jb2;
      const ushort_t* N1 = NVT + ((size_t)b * QKD + dp1) * NNODE + jb2;
#pragma unroll
      for (int ks = 0; ks < 4; ++ks) {
        kf[nxt][0][ks] = *(const bf16x8*)(K0 + ks * 32 + kg * 8);
        kf[nxt][1][ks] = *(const bf16x8*)(K1 + ks * 32 + kg * 8);
        nf[nxt][0][ks] = *(const bf16x8*)(N0 + ks * 32 + kg * 8);
        nf[nxt][1][ks] = *(const bf16x8*)(N1 + ks * 32 + kg * 8);
      }
      if (kg == 0) {
#pragma unroll
        for (int r = 0; r < 4; ++r) {
          const size_t off = (size_t)(rowbase + r) * NNODE + jb2;
          dd0[nxt][r] = dist[off + jl0]; mm0[nxt][r] = mask[off + jl0];
          dd1[nxt][r] = dist[off + jl1]; mm1[nxt][r] = mask[off + jl1];
        }
      } else {
#pragma unroll
        for (int r = 0; r < 4; ++r) {
          dd0[nxt][r] = 0.f; mm0[nxt][r] = 0;
          dd1[nxt][r] = 0.f; mm1[nxt][r] = 0;
        }
      }
      ee0[nxt] = edges[(size_t)(rowbase + wv) * NNODE + jb2 + lane];
      ee1[nxt] = edges[(size_t)(rowbase + wv) * NNODE + jb2 + 64 + lane];
    }

    // ---- QK^T: 8 MFMAs (2 j-tiles), operands fragment-shaped ------------
    {
      floatx4 sc0 = {0.f, 0.f, 0.f, 0.f};
      floatx4 sc1 = {0.f, 0.f, 0.f, 0.f};
#pragma unroll
      for (int ks = 0; ks < 4; ++ks) {
        sc0 = __builtin_amdgcn_mfma_f32_16x16x32_bf16(aq[ks], kf[cur][0][ks],
                                                      sc0, 0, 0, 0);
        sc1 = __builtin_amdgcn_mfma_f32_16x16x32_bf16(aq[ks], kf[cur][1][ks],
                                                      sc1, 0, 0, 0);
      }
      if (kg == 0) {                     // only real rows 0..3 stored
#pragma unroll
        for (int r = 0; r < 4; ++r) {
          float s0 = sc0[r] * coeff / (dd0[cur][r] + 1.0f);
          if (mm0[cur][r]) s0 = -__builtin_inff();
          sS[cur][r][jl0] = s0;
          float s1 = sc1[r] * coeff / (dd1[cur][r] + 1.0f);
          if (mm1[cur][r]) s1 = -__builtin_inff();
          sS[cur][r][jl1] = s1;
        }
      }
    }
    __syncthreads();

    // ---- online softmax: wave wv owns row wv; emit bf16 w to sWb --------
    {
      const float v0 = sS[cur][wv][lane];
      const float v1 = sS[cur][wv][lane + 64];
      float mc = fmaxf(v0, v1);
#pragma unroll
      for (int s = 1; s < 64; s <<= 1) mc = fmaxf(mc, __shfl_xor(mc, s, 64));
      const float mn = fmaxf(m_run, mc);
      const float f = (m_run > -__builtin_inff()) ? __expf(m_run - mn) : 0.f;
      float w0 = 0.f, w1 = 0.f;
      if (mn > -__builtin_inff()) {      // wave-uniform
        w0 = __expf(v0 - mn);
        w1 = __expf(v1 - mn);
      }
      const int j0 = lane, j1 = lane + 64;
      sWb[cur][wv][(j0 & ~31) + slot32(j0 & 31)] = f2bf(w0);
      sWb[cur][wv][(j1 & ~31) + slot32(j1 & 31)] = f2bf(w1);
      float lc = w0 + w1;
      float sec = fmaf(w0, ee0[cur], w1 * ee1[cur]);
#pragma unroll
      for (int s = 1; s < 64; s <<= 1) {
        lc  += __shfl_xor(lc, s, 64);
        sec += __shfl_xor(sec, s, 64);
      }
      l_run  = l_run * f + lc;
      se_run = se_run * f + sec;
      m_run  = mn;
      if (lane == 0) sF[wv] = f;
    }
    __syncthreads();

    // ---- PV: rescale accs; A = single b128 from sWb; B = prefetched -----
    {
      const float f0 = sF[kg * 4 + 0], f1 = sF[kg * 4 + 1];
      const float f2 = sF[kg * 4 + 2], f3 = sF[kg * 4 + 3];
      acc0[0] *= f0; acc0[1] *= f1; acc0[2] *= f2; acc0[3] *= f3;
      acc1[0] *= f0; acc1[1] *= f1; acc1[2] *= f2; acc1[3] *= f3;
#pragma unroll
      for (int ks = 0; ks < 4; ++ks) {
        const bf16x8 aw =
            *(const bf16x8*)(&sWb[cur][col][ks * 32 + kg * 8]);
        acc0 = __builtin_amdgcn_mfma_f32_16x16x32_bf16(aw, nf[cur][0][ks],
                                                       acc0, 0, 0, 0);
        acc1 = __builtin_amdgcn_mfma_f32_16x16x32_bf16(aw, nf[cur][1][ks],
                                                       acc1, 0, 0, 0);
      }
    }
    // hazards: sS[cur] rewritten by QK^T(c+2) after B2(c+1) ✓;
    // sWb[cur] rewritten by softmax(c+2) after B1(c+2) > PV(c) ✓.
  }

  // ---- epilogue: finalize row stats -------------------------------------
  {
    const float inv = (l_run > 0.f) ? 1.f / l_run : 0.f;
    if (lane == 0) {
      sF2[wv] = inv;
      sSe[wv] = se_run * inv;
      sSw[wv] = (l_run > 0.f) ? 1.f : 0.f;
    }
  }
  __syncthreads();

  // ---- normalize + tanh -> catb (bf16, slot-permuted k) ------------------
  if (kg == 0) {
#pragma unroll
    for (int r = 0; r < 4; ++r) {
      catb[r * CATB + kslot(dp0)] = f2bf(tanhf(acc0[r] * sF2[r]));
      catb[r * CATB + kslot(dp1)] = f2bf(tanhf(acc1[r] * sF2[r]));
    }
  }
  if (tid < RPB * EVD) {                 // 128 edge elems, d = 128+de
    const int r = tid >> 5, de = tid & 31;
    catb[r * CATB + 128 + slot32(de)] =
        f2bf(tanhf(fmaf(Wev[de], sSe[r], bev[de] * sSw[r])));
  }
  __syncthreads();

  // ---- transform: vals = catb @ Wtb^T + bt; all frags single b128 --------
  {
    bf16x8 af[5];
    const ushort_t* cr = catb + (size_t)(col & 3) * CATB;
#pragma unroll
    for (int ks = 0; ks < 5; ++ks)
      af[ks] = *(const bf16x8*)(cr + ks * 32 + kg * 8);
    float* sbuf = stats + (size_t)(bid & (NSTATBUF - 1)) * 2 * TRD;
#pragma unroll
    for (int t = 0; t < 4; ++t) {        // 16 col-tiles / 4 waves
      const int o = (wv * 4 + t) * 16 + col;
      const ushort_t* wr = Wtb + (size_t)o * CATD;
      floatx4 a2 = {0.f, 0.f, 0.f, 0.f};
#pragma unroll
      for (int ks = 0; ks < 5; ++ks) {
        const bf16x8 bf = *(const bf16x8*)(wr + ks * 32 + kg * 8);
        a2 = __builtin_amdgcn_mfma_f32_16x16x32_bf16(af[ks], bf, a2, 0, 0, 0);
      }
      const float bto = bt[o];
      float s1 = 0.f, s2 = 0.f;
#pragma unroll
      for (int r = 0; r < 4; ++r) {
        const float v2 = a2[r] + bto;
        if (kg == 0) {
          vals[(size_t)(rowbase + r) * TRD + o] = v2;
          s1 += v2;
          s2 = fmaf(v2, v2, s2);
        }
      }
      s1 += __shfl_xor(s1, 16, 64); s2 += __shfl_xor(s2, 16, 64);
      s1 += __shfl_xor(s1, 32, 64); s2 += __shfl_xor(s2, 32, 64);
      if (kg == 0) {
        atomicAdd(&sbuf[o], s1);
        atomicAdd(&sbuf[TRD + o], s2);
      }
    }
  }
}

// ---------------------------------------------------------------------------
// Kernel 3: fused BN-fold + classifier. 512 blocks x 256 thr, 4 rows/block.
// ---------------------------------------------------------------------------
__global__ __launch_bounds__(256) void outbn_kernel(
    const float* __restrict__ vals, const float* __restrict__ stats,
    const float* __restrict__ gamma, const float* __restrict__ beta,
    const float* __restrict__ Wc, const float* __restrict__ bc,
    float* __restrict__ out) {
  __shared__ float sW[NCLS][TRD];
  __shared__ float sb[NCLS];
  __shared__ float red[4][NCLS];
  const int tid = threadIdx.x;
  const int o = tid;                   // 0..255
  float s1 = 0.f, s2 = 0.f;
#pragma unroll
  for (int k = 0; k < NSTATBUF; ++k) {
    s1 += stats[k * 2 * TRD + o];
    s2 += stats[k * 2 * TRD + TRD + o];
  }
  const float invN = 1.0f / (float)NROWS;
  const float mu  = s1 * invN;
  const float var = s2 * invN - mu * mu;
  const float inv = 1.0f / sqrtf(var + EPSV);
  const float g = gamma[o] * inv;
  const float bterm = beta[o] - mu * g;
  float v[NCLS];
#pragma unroll
  for (int c = 0; c < NCLS; ++c) {
    const float wc = Wc[c * TRD + o];
    sW[c][o] = wc * g;
    v[c] = wc * bterm;
  }
#pragma unroll
  for (int s = 1; s < 64; s <<= 1) {
#pragma unroll
    for (int c = 0; c < NCLS; ++c) v[c] += __shfl_xor(v[c], s, 64);
  }
  if ((tid & 63) == 0) {
#pragma unroll
    for (int c = 0; c < NCLS; ++c) red[tid >> 6][c] = v[c];
  }
  __syncthreads();
  if (tid < NCLS)
    sb[tid] = bc[tid] + red[0][tid] + red[1][tid] + red[2][tid] + red[3][tid];
  __syncthreads();

  const int lane = tid & 63;
  const int row = blockIdx.x * 4 + (tid >> 6);
  float vv[TRD / 64];
#pragma unroll
  for (int t = 0; t < TRD / 64; ++t)
    vv[t] = vals[(size_t)row * TRD + lane + 64 * t];
#pragma unroll
  for (int c = 0; c < NCLS; ++c) {
    float p = 0.f;
#pragma unroll
    for (int t = 0; t < TRD / 64; ++t)
      p = fmaf(vv[t], sW[c][lane + 64 * t], p);
#pragma unroll
    for (int s = 1; s < 64; s <<= 1) p += __shfl_xor(p, s, 64);
    if (lane == 0) out[(size_t)row * NCLS + c] = p + sb[c];
  }
}

// ---------------------------------------------------------------------------
extern "C" void kernel_launch(void* const* d_in, const int* in_sizes, int n_in,
                              void* d_out, int out_size, void* d_ws, size_t ws_size,
                              hipStream_t stream) {
  (void)in_sizes; (void)n_in; (void)out_size; (void)ws_size;
  const float* nodes = (const float*)d_in[0];
  const float* edges = (const float*)d_in[1];
  const float* dist  = (const float*)d_in[2];
  const int*   mask  = (const int*)d_in[3];
  const float* Wq  = (const float*)d_in[4];
  const float* bq  = (const float*)d_in[5];
  const float* Wk  = (const float*)d_in[6];
  const float* bk  = (const float*)d_in[7];
  const float* Wnv = (const float*)d_in[8];
  const float* bnv = (const float*)d_in[9];
  const float* Wev = (const float*)d_in[10];
  const float* bev = (const float*)d_in[11];
  const float* Wt  = (const float*)d_in[12];
  const float* bt  = (const float*)d_in[13];
  const float* gamma = (const float*)d_in[14];
  const float* beta  = (const float*)d_in[15];
  const float* Wc  = (const float*)d_in[16];
  const float* bc  = (const float*)d_in[17];

  char* w = (char*)d_ws;
  ushort_t* Qb  = (ushort_t*)w;                w += (size_t)NROWS * QKD * 2;
  ushort_t* Kb  = (ushort_t*)w;                w += (size_t)NROWS * QKD * 2;
  ushort_t* NVT = (ushort_t*)w;                w += (size_t)NBATCH * QKD * NNODE * 2;
  ushort_t* Wtb = (ushort_t*)w;                w += (size_t)TRD * CATD * 2;
  float* vals  = (float*)w;                    w += (size_t)NROWS * TRD * 4;
  float* stats = (float*)w;
  float* outp  = (float*)d_out;

  qkv_kernel<<<NROWS / QR, 256, 0, stream>>>(nodes, Wq, bq, Wk, bk, Wnv, bnv,
                                             Wt, Qb, Kb, NVT, Wtb, stats);
  attnTrans_kernel<<<NROWS / RPB, 256, 0, stream>>>(
      Qb, Kb, NVT, edges, dist, mask, Wev, bev, Wtb, bt, vals, stats);
  outbn_kernel<<<NROWS / 4, 256, 0, stream>>>(vals, stats, gamma, beta,
                                              Wc, bc, outp);
}

// Round 17
// 31.137 us; speedup vs baseline: 1.3638x; 1.3638x over previous
//
#include <hip/hip_runtime.h>
#include <math.h>

#define NNODE 512
#define NBATCH 4
#define NFEAT 12
#define QKD 128
#define NVD 128
#define EVD 32
#define CATD 160          // NVD + EVD
#define CATB 168          // catb LDS stride (bf16)
#define TRD 256
#define NCLS 5
#define NROWS 2048        // NBATCH * NNODE
#define EPSV 1e-5f
#define NSTATBUF 8        // split BN-stat atomic contention 8 ways
#define JC2 256           // j-chunk width (2 chunks total)
#define RPB 8             // query rows per attnTrans block
#define QR 8              // rows per qkv block
#define SSW2 264          // sS row stride (f32)
#define WBW2 272          // sWb row stride (ushort, 544B = 16B-aligned)

typedef float floatx4 __attribute__((ext_vector_type(4)));
typedef __bf16 bf16x8 __attribute__((ext_vector_type(8)));
typedef unsigned short ushort_t;
typedef ushort_t ushort4v __attribute__((ext_vector_type(4)));

// f32 -> bf16 bits, round-to-nearest-even
static __device__ __forceinline__ ushort_t f2bf(float x) {
  unsigned int u = __float_as_uint(x);
  return (ushort_t)((u + 0x7fffu + ((u >> 16) & 1u)) >> 16);
}
// fragment k-order slot within a 32-block: lane kg holds logical k
// {4kg..4kg+3, 16+4kg..16+4kg+3}; slot32 places those 8 contiguously.
static __device__ __forceinline__ int slot32(int r) {   // r in 0..31
  return ((r & 15) >> 2) * 8 + (r & 3) + ((r >> 4) << 2);
}
static __device__ __forceinline__ int kslot(int k) {    // block-preserving
  return (k & ~31) + slot32(k & 31);
}

// ---------------------------------------------------------------------------
// Kernel 1: projections -> bf16 Qb[row][slot(d)], Kb[row][slot(d)],
// NVT[b][d][jslot], Wtb[o][slot(k)]. 256 blocks x 256 thr, 8 rows/block.
// (R15 verbatim.)
// ---------------------------------------------------------------------------
__global__ __launch_bounds__(256) void qkv_kernel(
    const float* __restrict__ nodes,
    const float* __restrict__ Wq, const float* __restrict__ bq,
    const float* __restrict__ Wk, const float* __restrict__ bk,
    const float* __restrict__ Wnv, const float* __restrict__ bnv,
    const float* __restrict__ Wt,
    ushort_t* __restrict__ Qb, ushort_t* __restrict__ Kb,
    ushort_t* __restrict__ NVT, ushort_t* __restrict__ Wtb,
    float* __restrict__ stats) {
  const int tid = threadIdx.x;
  const int blk = blockIdx.x;           // 0..255
  const int rowbase = blk * QR;
  const int b = rowbase >> 9;
  const int jloc = rowbase & (NNODE - 1);
  if (blk < 2 * NSTATBUF) stats[blk * 256 + tid] = 0.f;   // 16x256 = 4096
  // Wt -> bf16 slot-permuted: one o-row (o = blk) per block.
  if (tid < CATD)
    Wtb[(size_t)blk * CATD + kslot(tid)] = f2bf(Wt[(size_t)blk * CATD + tid]);
  __shared__ float sn[QR][NFEAT];
  if (tid < QR * NFEAT) ((float*)sn)[tid] = nodes[(size_t)rowbase * NFEAT + tid];
  __syncthreads();

  // ---- Q/K: thread owns d = tid&127; rows (tid>>7)*4 .. +3 --------------
  {
    const int d  = tid & 127;
    const int rg = tid >> 7;
    const int sd = kslot(d);            // permuted column
    float wq[NFEAT], wk[NFEAT];
#pragma unroll
    for (int k = 0; k < NFEAT; ++k) {
      wq[k] = Wq[d * NFEAT + k];
      wk[k] = Wk[d * NFEAT + k];
    }
    const float bqv = bq[d], bkv = bk[d];
#pragma unroll
    for (int rr = 0; rr < 4; ++rr) {
      const int rl = rg * 4 + rr;
      float aq = bqv, ak = bkv;
#pragma unroll
      for (int k = 0; k < NFEAT; ++k) {
        const float n = sn[rl][k];
        aq = fmaf(n, wq[k], aq);
        ak = fmaf(n, wk[k], ak);
      }
      Qb[(size_t)(rowbase + rl) * QKD + sd] = f2bf(aq);
      Kb[(size_t)(rowbase + rl) * QKD + sd] = f2bf(ak);
    }
  }
  // ---- NV^T: thread owns d = tid>>1, half = tid&1 (4 j each, j-slotted) --
  {
    const int d    = tid >> 1;
    const int half = tid & 1;
    float wnv[NFEAT];
#pragma unroll
    for (int k = 0; k < NFEAT; ++k) wnv[k] = Wnv[d * NFEAT + k];
    const float bnvv = bnv[d];
    ushort4v v;
#pragma unroll
    for (int e = 0; e < 4; ++e) {
      const int rl = half * 4 + e;
      float av = bnvv;
#pragma unroll
      for (int k = 0; k < NFEAT; ++k) av = fmaf(sn[rl][k], wnv[k], av);
      v[e] = f2bf(av);
    }
    const int js = jloc + half * 4;     // 4-aligned; slot(js+e)=slot(js)+e
    const int jsl = (js & ~31) + slot32(js & 31);
    *(ushort4v*)(NVT + (size_t)b * QKD * NNODE + (size_t)d * NNODE + jsl) = v;
  }
}

// ---------------------------------------------------------------------------
// Kernel 2: attnTrans — flash attention, lean data path (R15) with 2 chunks
// of 256 j instead of 4 of 128: barriers 10 -> 6, serial chain halved, same
// MFMA count and L2 traffic. 256 blocks (1/CU) x 512 thr (8 waves);
// wave wv: QK^T j-tiles {2wv,2wv+1}, PV d-tile wv, softmax row wv.
// ---------------------------------------------------------------------------
__global__ __launch_bounds__(512) void attnTrans_kernel(
    const ushort_t* __restrict__ Qb, const ushort_t* __restrict__ Kb,
    const ushort_t* __restrict__ NVT,
    const float* __restrict__ edges, const float* __restrict__ dist,
    const int* __restrict__ mask,
    const float* __restrict__ Wev, const float* __restrict__ bev,
    const ushort_t* __restrict__ Wtb, const float* __restrict__ bt,
    float* __restrict__ vals, float* __restrict__ stats) {
  __shared__ __align__(16) float sS[RPB][SSW2];        // 8.4 KB (scores)
  __shared__ __align__(16) ushort_t sWb[16][WBW2];     // 8.7 KB (bf16 w)
  __shared__ __align__(16) ushort_t catb[RPB * CATB];  // 2.7 KB
  __shared__ float sF[16], sF2[RPB], sSe[RPB], sSw[RPB];

  const int tid = threadIdx.x;
  const int bid = blockIdx.x;            // 0..255
  const int b   = bid >> 6;              // batch
  const int rg  = bid & 63;              // row group
  const int rowbase = b * NNODE + rg * RPB;

  const int lane = tid & 63;
  const int wv   = tid >> 6;             // wave 0..7
  const int col  = lane & 15;
  const int kg   = lane >> 4;

  if (tid < 16) sF[tid] = 0.f;           // rows 8..15 stay 0 forever

  const int jt0 = wv * 32 + col;         // chunk-local j, tile 2wv
  const int jt1 = jt0 + 16;              // tile 2wv+1
  const int dpv = wv * 16 + col;         // d column (PV)

  // ---- Q A-fragments: single b128 each (slot-permuted Qb) ----------------
  bf16x8 aq[4];
  {
    const ushort_t* Qr = Qb + (size_t)(rowbase + (col & 7)) * QKD;
#pragma unroll
    for (int ks = 0; ks < 4; ++ks)
      aq[ks] = *(const bf16x8*)(Qr + ks * 32 + kg * 8);
  }

  // ---- chunk 0 loads -----------------------------------------------------
  bf16x8 k0a[4], k0b[4], n0[8];
  float dd0a[4], dd0b[4]; int mm0a[4], mm0b[4]; float e0[4];
  {
    const ushort_t* K0 = Kb + (size_t)(b * NNODE + jt0) * QKD;
    const ushort_t* K1 = Kb + (size_t)(b * NNODE + jt1) * QKD;
    const ushort_t* Nr = NVT + ((size_t)b * QKD + dpv) * NNODE;
#pragma unroll
    for (int ks = 0; ks < 4; ++ks) {
      k0a[ks] = *(const bf16x8*)(K0 + ks * 32 + kg * 8);
      k0b[ks] = *(const bf16x8*)(K1 + ks * 32 + kg * 8);
    }
#pragma unroll
    for (int ks = 0; ks < 8; ++ks)
      n0[ks] = *(const bf16x8*)(Nr + ks * 32 + kg * 8);
#pragma unroll
    for (int r = 0; r < 4; ++r) {
      const size_t off = (size_t)(rowbase + ((kg * 4 + r) & 7)) * NNODE;
      dd0a[r] = dist[off + jt0]; mm0a[r] = mask[off + jt0];
      dd0b[r] = dist[off + jt1]; mm0b[r] = mask[off + jt1];
    }
#pragma unroll
    for (int t = 0; t < 4; ++t)
      e0[t] = edges[(size_t)(rowbase + wv) * NNODE + lane + 64 * t];
  }

  float m_run = -__builtin_inff(), l_run = 0.f, se_run = 0.f;  // row = wv
  floatx4 acc = {0.f, 0.f, 0.f, 0.f};    // PV acc (rows kg*4+r, col dpv)
  const float coeff = 0.0883883476483184f;  // 1/sqrt(128)

  // ======== chunk 0: QK^T =================================================
  {
    floatx4 sc0 = {0.f, 0.f, 0.f, 0.f};
    floatx4 sc1 = {0.f, 0.f, 0.f, 0.f};
#pragma unroll
    for (int ks = 0; ks < 4; ++ks) {
      sc0 = __builtin_amdgcn_mfma_f32_16x16x32_bf16(aq[ks], k0a[ks], sc0, 0, 0, 0);
      sc1 = __builtin_amdgcn_mfma_f32_16x16x32_bf16(aq[ks], k0b[ks], sc1, 0, 0, 0);
    }
    if (kg < 2) {                        // real rows 0..7
#pragma unroll
      for (int r = 0; r < 4; ++r) {
        float s0 = sc0[r] * coeff / (dd0a[r] + 1.0f);
        if (mm0a[r]) s0 = -__builtin_inff();
        sS[kg * 4 + r][jt0] = s0;
        float s1 = sc1[r] * coeff / (dd0b[r] + 1.0f);
        if (mm0b[r]) s1 = -__builtin_inff();
        sS[kg * 4 + r][jt1] = s1;
      }
    }
  }
  // ---- issue chunk 1 loads (in flight across SM0+PV0) --------------------
  bf16x8 k1a[4], k1b[4], n1[8];
  float dd1a[4], dd1b[4]; int mm1a[4], mm1b[4]; float e1[4];
  {
    const ushort_t* K0 = Kb + (size_t)(b * NNODE + JC2 + jt0) * QKD;
    const ushort_t* K1 = Kb + (size_t)(b * NNODE + JC2 + jt1) * QKD;
    const ushort_t* Nr = NVT + ((size_t)b * QKD + dpv) * NNODE + JC2;
#pragma unroll
    for (int ks = 0; ks < 4; ++ks) {
      k1a[ks] = *(const bf16x8*)(K0 + ks * 32 + kg * 8);
      k1b[ks] = *(const bf16x8*)(K1 + ks * 32 + kg * 8);
    }
#pragma unroll
    for (int ks = 0; ks < 8; ++ks)
      n1[ks] = *(const bf16x8*)(Nr + ks * 32 + kg * 8);
#pragma unroll
    for (int r = 0; r < 4; ++r) {
      const size_t off = (size_t)(rowbase + ((kg * 4 + r) & 7)) * NNODE + JC2;
      dd1a[r] = dist[off + jt0]; mm1a[r] = mask[off + jt0];
      dd1b[r] = dist[off + jt1]; mm1b[r] = mask[off + jt1];
    }
#pragma unroll
    for (int t = 0; t < 4; ++t)
      e1[t] = edges[(size_t)(rowbase + wv) * NNODE + JC2 + lane + 64 * t];
  }
  __syncthreads();                       // bar1: sS chunk-0 visible

  // ---- chunk 0: online softmax (wave wv -> row wv, 256 j) ----------------
  {
    float v[4];
#pragma unroll
    for (int t = 0; t < 4; ++t) v[t] = sS[wv][lane + 64 * t];
    float mc = fmaxf(fmaxf(v[0], v[1]), fmaxf(v[2], v[3]));
#pragma unroll
    for (int s = 1; s < 64; s <<= 1) mc = fmaxf(mc, __shfl_xor(mc, s, 64));
    const float mn = fmaxf(m_run, mc);
    const float f = (m_run > -__builtin_inff()) ? __expf(m_run - mn) : 0.f;
    float w[4], lc = 0.f, sec = 0.f;
#pragma unroll
    for (int t = 0; t < 4; ++t) {
      w[t] = (mn > -__builtin_inff()) ? __expf(v[t] - mn) : 0.f;
      const int j = lane + 64 * t;
      sWb[wv][(j & ~31) + slot32(j & 31)] = f2bf(w[t]);
      lc += w[t];
      sec = fmaf(w[t], e0[t], sec);
    }
#pragma unroll
    for (int s = 1; s < 64; s <<= 1) {
      lc  += __shfl_xor(lc, s, 64);
      sec += __shfl_xor(sec, s, 64);
    }
    l_run  = l_run * f + lc;
    se_run = se_run * f + sec;
    m_run  = mn;
    if (lane == 0) sF[wv] = f;
  }
  __syncthreads();                       // bar2: sWb chunk-0 visible

  // ---- chunk 0: PV (rescale + 8 MFMAs) -----------------------------------
  {
    acc[0] *= sF[kg * 4 + 0];
    acc[1] *= sF[kg * 4 + 1];
    acc[2] *= sF[kg * 4 + 2];
    acc[3] *= sF[kg * 4 + 3];
#pragma unroll
    for (int ks = 0; ks < 8; ++ks) {
      const bf16x8 aw = *(const bf16x8*)(&sWb[col][ks * 32 + kg * 8]);
      acc = __builtin_amdgcn_mfma_f32_16x16x32_bf16(aw, n0[ks], acc, 0, 0, 0);
    }
  }

  // ======== chunk 1: QK^T (sS safe: all SM0 reads done at bar2) ===========
  {
    floatx4 sc0 = {0.f, 0.f, 0.f, 0.f};
    floatx4 sc1 = {0.f, 0.f, 0.f, 0.f};
#pragma unroll
    for (int ks = 0; ks < 4; ++ks) {
      sc0 = __builtin_amdgcn_mfma_f32_16x16x32_bf16(aq[ks], k1a[ks], sc0, 0, 0, 0);
      sc1 = __builtin_amdgcn_mfma_f32_16x16x32_bf16(aq[ks], k1b[ks], sc1, 0, 0, 0);
    }
    if (kg < 2) {
#pragma unroll
      for (int r = 0; r < 4; ++r) {
        float s0 = sc0[r] * coeff / (dd1a[r] + 1.0f);
        if (mm1a[r]) s0 = -__builtin_inff();
        sS[kg * 4 + r][jt0] = s0;
        float s1 = sc1[r] * coeff / (dd1b[r] + 1.0f);
        if (mm1b[r]) s1 = -__builtin_inff();
        sS[kg * 4 + r][jt1] = s1;
      }
    }
  }
  __syncthreads();                       // bar3: sS chunk-1 visible;
                                         // also: all PV0 sWb reads done
  // ---- chunk 1: online softmax -------------------------------------------
  {
    float v[4];
#pragma unroll
    for (int t = 0; t < 4; ++t) v[t] = sS[wv][lane + 64 * t];
    float mc = fmaxf(fmaxf(v[0], v[1]), fmaxf(v[2], v[3]));
#pragma unroll
    for (int s = 1; s < 64; s <<= 1) mc = fmaxf(mc, __shfl_xor(mc, s, 64));
    const float mn = fmaxf(m_run, mc);
    const float f = (m_run > -__builtin_inff()) ? __expf(m_run - mn) : 0.f;
    float w[4], lc = 0.f, sec = 0.f;
#pragma unroll
    for (int t = 0; t < 4; ++t) {
      w[t] = (mn > -__builtin_inff()) ? __expf(v[t] - mn) : 0.f;
      const int j = lane + 64 * t;
      sWb[wv][(j & ~31) + slot32(j & 31)] = f2bf(w[t]);
      lc += w[t];
      sec = fmaf(w[t], e1[t], sec);
    }
#pragma unroll
    for (int s = 1; s < 64; s <<= 1) {
      lc  += __shfl_xor(lc, s, 64);
      sec += __shfl_xor(sec, s, 64);
    }
    l_run  = l_run * f + lc;
    se_run = se_run * f + sec;
    m_run  = mn;
    if (lane == 0) sF[wv] = f;
  }
  __syncthreads();                       // bar4: sWb chunk-1 visible

  // ---- chunk 1: PV --------------------------------------------------------
  {
    acc[0] *= sF[kg * 4 + 0];
    acc[1] *= sF[kg * 4 + 1];
    acc[2] *= sF[kg * 4 + 2];
    acc[3] *= sF[kg * 4 + 3];
#pragma unroll
    for (int ks = 0; ks < 8; ++ks) {
      const bf16x8 aw = *(const bf16x8*)(&sWb[col][ks * 32 + kg * 8]);
      acc = __builtin_amdgcn_mfma_f32_16x16x32_bf16(aw, n1[ks], acc, 0, 0, 0);
    }
  }

  // ---- epilogue: finalize row stats --------------------------------------
  {
    const float inv = (l_run > 0.f) ? 1.f / l_run : 0.f;
    if (lane == 0) {
      sF2[wv] = inv;
      sSe[wv] = se_run * inv;
      sSw[wv] = (l_run > 0.f) ? 1.f : 0.f;
    }
  }
  __syncthreads();                       // bar5

  // ---- normalize + tanh -> catb (bf16, slot-permuted k) -------------------
  if (kg < 2) {
#pragma unroll
    for (int r = 0; r < 4; ++r) {
      const int row = kg * 4 + r;
      catb[row * CATB + kslot(dpv)] = f2bf(tanhf(acc[r] * sF2[row]));
    }
  }
  if (tid < RPB * EVD) {                 // 256 edge elems, d = 128+de
    const int r = tid >> 5, de = tid & 31;
    catb[r * CATB + 128 + slot32(de)] =
        f2bf(tanhf(fmaf(Wev[de], sSe[r], bev[de] * sSw[r])));
  }
  __syncthreads();                       // bar6

  // ---- transform: vals = catb @ Wtb^T + bt; all frags single b128 ---------
  {
    bf16x8 af[5];
    const ushort_t* cr = catb + (size_t)(col & 7) * CATB;
#pragma unroll
    for (int ks = 0; ks < 5; ++ks)
      af[ks] = *(const bf16x8*)(cr + ks * 32 + kg * 8);
    float* sbuf = stats + (size_t)(bid & (NSTATBUF - 1)) * 2 * TRD;
#pragma unroll
    for (int t = 0; t < 2; ++t) {        // 16 col-tiles / 8 waves
      const int o = (wv * 2 + t) * 16 + col;
      const ushort_t* wr = Wtb + (size_t)o * CATD;
      floatx4 a2 = {0.f, 0.f, 0.f, 0.f};
#pragma unroll
      for (int ks = 0; ks < 5; ++ks) {
        const bf16x8 bf = *(const bf16x8*)(wr + ks * 32 + kg * 8);
        a2 = __builtin_amdgcn_mfma_f32_16x16x32_bf16(af[ks], bf, a2, 0, 0, 0);
      }
      const float bto = bt[o];
      float s1 = 0.f, s2 = 0.f;
#pragma unroll
      for (int r = 0; r < 4; ++r) {
        const float v2 = a2[r] + bto;
        if (kg < 2) {
          vals[(size_t)(rowbase + kg * 4 + r) * TRD + o] = v2;
          s1 += v2;
          s2 = fmaf(v2, v2, s2);
        }
      }
      s1 += __shfl_xor(s1, 16, 64); s2 += __shfl_xor(s2, 16, 64);
      s1 += __shfl_xor(s1, 32, 64); s2 += __shfl_xor(s2, 32, 64);
      if (kg == 0) {
        atomicAdd(&sbuf[o], s1);
        atomicAdd(&sbuf[TRD + o], s2);
      }
    }
  }
}

// ---------------------------------------------------------------------------
// Kernel 3: fused BN-fold + classifier. 512 blocks x 256 thr, 4 rows/block.
// (R15 verbatim.)
// ---------------------------------------------------------------------------
__global__ __launch_bounds__(256) void outbn_kernel(
    const float* __restrict__ vals, const float* __restrict__ stats,
    const float* __restrict__ gamma, const float* __restrict__ beta,
    const float* __restrict__ Wc, const float* __restrict__ bc,
    float* __restrict__ out) {
  __shared__ float sW[NCLS][TRD];
  __shared__ float sb[NCLS];
  __shared__ float red[4][NCLS];
  const int tid = threadIdx.x;
  const int o = tid;                   // 0..255
  float s1 = 0.f, s2 = 0.f;
#pragma unroll
  for (int k = 0; k < NSTATBUF; ++k) {
    s1 += stats[k * 2 * TRD + o];
    s2 += stats[k * 2 * TRD + TRD + o];
  }
  const float invN = 1.0f / (float)NROWS;
  const float mu  = s1 * invN;
  const float var = s2 * invN - mu * mu;
  const float inv = 1.0f / sqrtf(var + EPSV);
  const float g = gamma[o] * inv;
  const float bterm = beta[o] - mu * g;
  float v[NCLS];
#pragma unroll
  for (int c = 0; c < NCLS; ++c) {
    const float wc = Wc[c * TRD + o];
    sW[c][o] = wc * g;
    v[c] = wc * bterm;
  }
#pragma unroll
  for (int s = 1; s < 64; s <<= 1) {
#pragma unroll
    for (int c = 0; c < NCLS; ++c) v[c] += __shfl_xor(v[c], s, 64);
  }
  if ((tid & 63) == 0) {
#pragma unroll
    for (int c = 0; c < NCLS; ++c) red[tid >> 6][c] = v[c];
  }
  __syncthreads();
  if (tid < NCLS)
    sb[tid] = bc[tid] + red[0][tid] + red[1][tid] + red[2][tid] + red[3][tid];
  __syncthreads();

  const int lane = tid & 63;
  const int row = blockIdx.x * 4 + (tid >> 6);
  float vv[TRD / 64];
#pragma unroll
  for (int t = 0; t < TRD / 64; ++t)
    vv[t] = vals[(size_t)row * TRD + lane + 64 * t];
#pragma unroll
  for (int c = 0; c < NCLS; ++c) {
    float p = 0.f;
#pragma unroll
    for (int t = 0; t < TRD / 64; ++t)
      p = fmaf(vv[t], sW[c][lane + 64 * t], p);
#pragma unroll
    for (int s = 1; s < 64; s <<= 1) p += __shfl_xor(p, s, 64);
    if (lane == 0) out[(size_t)row * NCLS + c] = p + sb[c];
  }
}

// ---------------------------------------------------------------------------
extern "C" void kernel_launch(void* const* d_in, const int* in_sizes, int n_in,
                              void* d_out, int out_size, void* d_ws, size_t ws_size,
                              hipStream_t stream) {
  (void)in_sizes; (void)n_in; (void)out_size; (void)ws_size;
  const float* nodes = (const float*)d_in[0];
  const float* edges = (const float*)d_in[1];
  const float* dist  = (const float*)d_in[2];
  const int*   mask  = (const int*)d_in[3];
  const float* Wq  = (const float*)d_in[4];
  const float* bq  = (const float*)d_in[5];
  const float* Wk  = (const float*)d_in[6];
  const float* bk  = (const float*)d_in[7];
  const float* Wnv = (const float*)d_in[8];
  const float* bnv = (const float*)d_in[9];
  const float* Wev = (const float*)d_in[10];
  const float* bev = (const float*)d_in[11];
  const float* Wt  = (const float*)d_in[12];
  const float* bt  = (const float*)d_in[13];
  const float* gamma = (const float*)d_in[14];
  const float* beta  = (const float*)d_in[15];
  const float* Wc  = (const float*)d_in[16];
  const float* bc  = (const float*)d_in[17];

  char* w = (char*)d_ws;
  ushort_t* Qb  = (ushort_t*)w;                w += (size_t)NROWS * QKD * 2;
  ushort_t* Kb  = (ushort_t*)w;                w += (size_t)NROWS * QKD * 2;
  ushort_t* NVT = (ushort_t*)w;                w += (size_t)NBATCH * QKD * NNODE * 2;
  ushort_t* Wtb = (ushort_t*)w;                w += (size_t)TRD * CATD * 2;
  float* vals  = (float*)w;                    w += (size_t)NROWS * TRD * 4;
  float* stats = (float*)w;
  float* outp  = (float*)d_out;

  qkv_kernel<<<NROWS / QR, 256, 0, stream>>>(nodes, Wq, bq, Wk, bk, Wnv, bnv,
                                             Wt, Qb, Kb, NVT, Wtb, stats);
  attnTrans_kernel<<<NROWS / RPB, 512, 0, stream>>>(
      Qb, Kb, NVT, edges, dist, mask, Wev, bev, Wtb, bt, vals, stats);
  outbn_kernel<<<NROWS / 4, 256, 0, stream>>>(vals, stats, gamma, beta,
                                              Wc, bc, outp);
}